// Round 13
// baseline (333.091 us; speedup 1.0000x reference)
//
#include <hip/hip_runtime.h>
#include <hip/hip_cooperative_groups.h>
#include <math.h>

namespace cg = cooperative_groups;

#define Mv 8
#define Nv 8192
#define Kv 256
#define BPM 32            // blocks per m -> 256 blocks x 512 threads (1/CU!)
#define NBLK (Mv*BPM)     // 256
#define TPB 512
#define NITER 6
#define EPSILON_C 0.01f
#define GAMMA_C 0.005f

// ws layout (float offsets)
#define WS_R     0        // 72
#define WS_T     72       // 24
#define WS_X     96       // 768
#define WS_Q     864      // 256
#define WS_BETA  1120     // 1
#define WS_ACC   1124     // 3 x ACCSZ
#define AC_STATS 0        // 128 (M x 16)
#define AC_L     128      // 2048 (M x K)
#define AC_W     2176     // 6144 (M x 3 x K)
#define AC_H     8320     // 2048 (M x K)
#define ACCSZ    10368

#define ALD(p) __hip_atomic_load((p), __ATOMIC_RELAXED, __HIP_MEMORY_SCOPE_AGENT)
#define AST(p,v) __hip_atomic_store((p), (v), __ATOMIC_RELAXED, __HIP_MEMORY_SCOPE_AGENT)

// ---- wave-wide sum via DPP; wave-uniform result. All 64 lanes must be active.
__device__ __forceinline__ float wave_red_sum(float x) {
  int v;
  float t;
  v = __builtin_bit_cast(int, x);
  t = __builtin_bit_cast(float, __builtin_amdgcn_update_dpp(0, v, 0x111, 0xf, 0xf, true));  // row_shr:1
  x += t; v = __builtin_bit_cast(int, x);
  t = __builtin_bit_cast(float, __builtin_amdgcn_update_dpp(0, v, 0x112, 0xf, 0xf, true));  // row_shr:2
  x += t; v = __builtin_bit_cast(int, x);
  t = __builtin_bit_cast(float, __builtin_amdgcn_update_dpp(0, v, 0x114, 0xf, 0xf, true));  // row_shr:4
  x += t; v = __builtin_bit_cast(int, x);
  t = __builtin_bit_cast(float, __builtin_amdgcn_update_dpp(0, v, 0x118, 0xf, 0xf, true));  // row_shr:8
  x += t; v = __builtin_bit_cast(int, x);
  t = __builtin_bit_cast(float, __builtin_amdgcn_update_dpp(0, v, 0x142, 0xa, 0xf, false)); // row_bcast:15
  x += t; v = __builtin_bit_cast(int, x);
  t = __builtin_bit_cast(float, __builtin_amdgcn_update_dpp(0, v, 0x143, 0xc, 0xf, false)); // row_bcast:31
  x += t;
  return __builtin_bit_cast(float, __builtin_amdgcn_readlane(__builtin_bit_cast(int, x), 63));
}

// ---------------------------------------------------------------- init
__global__ __launch_bounds__(256) void p0_init(const float* __restrict__ Vs,
                                               const float* __restrict__ X0,
                                               const float* __restrict__ Q0,
                                               float* __restrict__ ws) {
  __shared__ float sred[4];
  int tid = threadIdx.x;
  int b = blockIdx.x;
  int wave = tid >> 6, lane = tid & 63;
  if (b < 24) {
    int m = b / 3, d = b % 3;
    const float* src = Vs + (size_t)(m*3 + d) * Nv;
    float s = 0.f;
    for (int n = tid; n < Nv; n += 256) s += src[n];
    s = wave_red_sum(s);
    if (lane == 0) sred[wave] = s;
    __syncthreads();
    if (tid == 0) {
      float tot = sred[0]+sred[1]+sred[2]+sred[3];
      ws[WS_T + m*3 + d] = -tot / (float)Nv;
    }
    if (d == 0 && tid < 9) {
      ws[WS_R + m*9 + tid] = (tid==0||tid==4||tid==8) ? 1.f : 0.f;
    }
  } else {
    float s = (tid < Kv) ? Q0[tid] : 0.f;
    s = wave_red_sum(s);
    if (lane == 0) sred[wave] = s;
    __syncthreads();
    if (tid == 0) {
      float mq = (sred[0]+sred[1]+sred[2]+sred[3]) / (float)Kv;
      ws[WS_BETA] = GAMMA_C * mq * sqrtf(mq);
    }
    if (tid < Kv) ws[WS_Q + tid] = Q0[tid];
    for (int i = tid; i < Kv*3; i += 256) ws[WS_X + i] = X0[i];
    // zero acc buffer 0 (buffers 1,2 zeroed inside p_main iterations 0,1)
    for (int i = tid; i < ACCSZ; i += 256) ws[WS_ACC + i] = 0.f;
  }
}

// ---- fp32 Jacobi rotation, COMPILE-TIME pair, named scalars only.
#define JROTF(app,aqq,apq,apr,aqr, vp0,vp1,vp2, vq0,vq1,vq2) do {           \
    float tau_ = (aqq - app) * __builtin_amdgcn_rcpf(2.0f*apq);             \
    float tt_ = __builtin_amdgcn_rcpf(fabsf(tau_) +                         \
                   __builtin_amdgcn_sqrtf(fmaf(tau_,tau_,1.0f)));           \
    tt_ = (tau_ < 0.0f) ? -tt_ : tt_;                                       \
    tt_ = (apq == 0.0f) ? 0.0f : tt_;                                       \
    float c_ = __builtin_amdgcn_rsqf(fmaf(tt_,tt_,1.0f)), s_ = tt_*c_;      \
    float papq_ = apq;                                                      \
    app = fmaf(-tt_,papq_,app); aqq = fmaf(tt_,papq_,aqq); apq = 0.0f;      \
    float tp_ = apr, tq_ = aqr;                                             \
    apr = c_*tp_ - s_*tq_; aqr = s_*tp_ + c_*tq_;                           \
    tp_=vp0; tq_=vq0; vp0=c_*tp_-s_*tq_; vq0=s_*tp_+c_*tq_;                 \
    tp_=vp1; tq_=vq1; vp1=c_*tp_-s_*tq_; vq1=s_*tp_+c_*tq_;                 \
    tp_=vp2; tq_=vq2; vp2=c_*tp_-s_*tq_; vq2=s_*tp_+c_*tq_;                 \
  } while(0)

#define CSWAP3F(la,lb, a0,a1,a2, b0,b1,b2) do {                             \
    if (la < lb) { float t_;                                                \
      t_=la; la=lb; lb=t_; t_=a0; a0=b0; b0=t_;                             \
      t_=a1; a1=b1; b1=t_; t_=a2; a2=b2; b2=t_; }                           \
  } while(0)

// ---------------------------------------------- persistent cooperative kernel
// 256 blocks x 512 threads (8 waves) — 1 block/CU, so cooperative occupancy
// validation is trivially satisfied (R12's 512x256 @2/CU likely failed launch).
// One grid.sync() per iteration. Phase A: accumulate L/W/H + 16 per-m stats
// into triple-buffered acc via atomics (proven R8 path). Phase B (redundant
// per block): per-k X/Q update + 8-lane solve from totals; state in LDS.
__global__ __launch_bounds__(TPB, 2) void p_main(const float* __restrict__ Vs,
                                                 float* __restrict__ ws) {
  __shared__ float sb[8][5][Kv];   // 40 KB phase-A staging
  __shared__ float st4[4][16];
  __shared__ float sX[Kv][3];
  __shared__ float sQ[Kv];
  __shared__ float sR[Mv][9];
  __shared__ float sT[Mv][3];
  __shared__ float sTn[Mv];

  cg::grid_group grid = cg::this_grid();
  int tid  = threadIdx.x;
  int wave = tid >> 6, lane = tid & 63;
  int bid  = blockIdx.x;
  int m    = bid / BPM;
  int blk  = bid % BPM;
  int wid  = blk*8 + wave;   // 0..255
  const int k = tid;         // valid for tid<256 per-k ops
  float beta = ws[WS_BETA];

  // bootstrap state from p0
  if (tid < 72) ((float*)sR)[tid] = ws[WS_R + tid];
  if (tid < 24) ((float*)sT)[tid] = ws[WS_T + tid];
  if (tid < Kv) {
    sX[k][0] = ws[WS_X + 3*k+0];
    sX[k][1] = ws[WS_X + 3*k+1];
    sX[k][2] = ws[WS_X + 3*k+2];
    sQ[k]    = ws[WS_Q + k];
  }

  const float* V0 = Vs + (size_t)(m*3+0)*Nv;
  const float* V1 = Vs + (size_t)(m*3+1)*Nv;
  const float* V2 = Vs + (size_t)(m*3+2)*Nv;

  for (int it = 0; it < NITER; ++it) {
    __syncthreads();   // state LDS writes (bootstrap / prev B) -> A reads
    float* acc  = ws + WS_ACC + (it % 3)*ACCSZ;
    float* accz = ws + WS_ACC + ((it+1) % 3)*ACCSZ;
    // zero next buffer; last reader was B(it-2), complete before sync(it-1)
    { int z = bid*41 + tid;
      if (tid < 41 && z < ACCSZ) AST(&accz[z], 0.f); }

    // ---- phase A (all 8 waves)
    float R00=sR[m][0],R01=sR[m][1],R02=sR[m][2];
    float R10=sR[m][3],R11=sR[m][4],R12=sR[m][5];
    float R20=sR[m][6],R21=sR[m][7],R22=sR[m][8];
    float t0=sT[m][0], t1=sT[m][1], t2=sT[m][2];
    float kXx[4],kXy[4],kXz[4],kA[4],kB[4],kQ[4],kQ32[4];
    #pragma unroll
    for (int j=0;j<4;j++) {
      int kk = lane + 64*j;
      float xx = sX[kk][0], xy = sX[kk][1], xz = sX[kk][2];
      float q  = sQ[kk];
      kXx[j]=xx; kXy[j]=xy; kXz[j]=xz;
      kA[j]  = -0.5f*q;
      kB[j]  = kA[j]*(xx*xx+xy*xy+xz*xz);
      kQ[j]  = q;
      kQ32[j]= q*sqrtf(q);
    }
    float aL[4]={0,0,0,0}, aWx[4]={0,0,0,0}, aWy[4]={0,0,0,0},
          aWz[4]={0,0,0,0}, aH[4]={0,0,0,0};
    for (int n = wid; n < Nv; n += 256) {
      float vx = V0[n], vy = V1[n], vz = V2[n];
      float px = fmaf(R00,vx, fmaf(R01,vy, fmaf(R02,vz, t0)));
      float py = fmaf(R10,vx, fmaf(R11,vy, fmaf(R12,vz, t1)));
      float pz = fmaf(R20,vx, fmaf(R21,vy, fmaf(R22,vz, t2)));
      float tvn = fmaf(px,px, fmaf(py,py, pz*pz));
      float vn  = fmaf(vx,vx, fmaf(vy,vy, vz*vz));
      float ap[4]; float s = 0.f;
      #pragma unroll
      for (int j=0;j<4;j++) {
        float dot = fmaf(px,kXx[j], fmaf(py,kXy[j], pz*kXz[j]));
        float arg = fmaf(kQ[j], dot, fmaf(kA[j], tvn, kB[j]));
        float e = __expf(arg)*kQ32[j];
        ap[j] = e; s += e;
      }
      float S = wave_red_sum(s);
      float inv = __builtin_amdgcn_rcpf(S + beta);
      #pragma unroll
      for (int j=0;j<4;j++) {
        float a = ap[j]*inv;
        aL[j] += a;
        aWx[j] = fmaf(a,vx,aWx[j]);
        aWy[j] = fmaf(a,vy,aWy[j]);
        aWz[j] = fmaf(a,vz,aWz[j]);
        aH[j]  = fmaf(a,vn,aH[j]);
      }
    }
    #pragma unroll
    for (int j=0;j<4;j++) {
      int kk = lane + 64*j;
      sb[wave][0][kk]=aL[j];  sb[wave][1][kk]=aWx[j]; sb[wave][2][kk]=aWy[j];
      sb[wave][3][kk]=aWz[j]; sb[wave][4][kk]=aH[j];
    }
    __syncthreads();
    if (tid < Kv) {  // waves 0..3, all lanes active
      const int k2 = (tid + 8*blk) & (Kv-1);   // decorrelate atomic targets
      float vL=0.f, vWx=0.f, vWy=0.f, vWz=0.f, vH=0.f;
      #pragma unroll
      for (int w=0; w<8; w++) {
        vL  += sb[w][0][k2]; vWx += sb[w][1][k2]; vWy += sb[w][2][k2];
        vWz += sb[w][3][k2]; vH  += sb[w][4][k2];
      }
      atomicAdd(&acc[AC_L + m*Kv + k2], vL);
      atomicAdd(&acc[AC_W + (m*3+0)*Kv + k2], vWx);
      atomicAdd(&acc[AC_W + (m*3+1)*Kv + k2], vWy);
      atomicAdd(&acc[AC_W + (m*3+2)*Kv + k2], vWz);
      atomicAdd(&acc[AC_H + m*Kv + k2], vH);
      // stats partials (linear in L/W)
      float q  = sQ[k2];
      float x0 = sX[k2][0], x1 = sX[k2][1], x2 = sX[k2][2];
      float bk = vL*q;
      float sw0 = vWx*q, sw1 = vWy*q, sw2 = vWz*q;
      float pr[16];
      pr[0]=bk;  pr[1]=bk*x0; pr[2]=bk*x1; pr[3]=bk*x2;
      pr[4]=sw0; pr[5]=sw1;   pr[6]=sw2;
      pr[7]=sw0*x0;  pr[8]=sw1*x0;  pr[9]=sw2*x0;
      pr[10]=sw0*x1; pr[11]=sw1*x1; pr[12]=sw2*x1;
      pr[13]=sw0*x2; pr[14]=sw1*x2; pr[15]=sw2*x2;
      float red[16];
      #pragma unroll
      for (int v2=0; v2<16; v2++) red[v2] = wave_red_sum(pr[v2]);
      if (lane == 0) {
        #pragma unroll
        for (int v2=0; v2<16; v2++) st4[wave][v2] = red[v2];
      }
    }
    __syncthreads();
    if (tid < 16) {
      int j = (tid + blk) & 15;
      atomicAdd(&acc[AC_STATS + m*16 + j],
                st4[0][j]+st4[1][j]+st4[2][j]+st4[3][j]);
    }

    grid.sync();   // all atomics complete & visible

    // ---- phase B (redundant per block)
    float lk[Mv], w0v[Mv], w1v[Mv], w2v[Mv], hk[Mv];
    if (tid < Kv) {
      #pragma unroll
      for (int mm=0;mm<Mv;mm++) {
        lk[mm]  = ALD(&acc[AC_L + mm*Kv + k]);
        w0v[mm] = ALD(&acc[AC_W + (mm*3+0)*Kv + k]);
        w1v[mm] = ALD(&acc[AC_W + (mm*3+1)*Kv + k]);
        w2v[mm] = ALD(&acc[AC_W + (mm*3+2)*Kv + k]);
        hk[mm]  = ALD(&acc[AC_H + mm*Kv + k]);
      }
    }
    if (tid < Mv) {
      int mm = tid;
      const float* st = acc + AC_STATS + mm*16;
      float s0=ALD(&st[0]), s1=ALD(&st[1]), s2v=ALD(&st[2]), s3=ALD(&st[3]),
            s4=ALD(&st[4]), s5=ALD(&st[5]), s6=ALD(&st[6]), s7=ALD(&st[7]),
            s8=ALD(&st[8]), s9=ALD(&st[9]), s10=ALD(&st[10]), s11=ALD(&st[11]),
            s12=ALD(&st[12]), s13=ALD(&st[13]), s14=ALD(&st[14]), s15=ALD(&st[15]);
      float z = s0;
      float mX0 = s1, mX1 = s2v, mX2 = s3;
      float mW0 = s4, mW1 = s5, mW2 = s6;
      float iz = __builtin_amdgcn_rcpf(z);
      float P00 = s7  - mX0*mW0*iz;
      float P01 = s8  - mX0*mW1*iz;
      float P02 = s9  - mX0*mW2*iz;
      float P10 = s10 - mX1*mW0*iz;
      float P11 = s11 - mX1*mW1*iz;
      float P12 = s12 - mX1*mW2*iz;
      float P20 = s13 - mX2*mW0*iz;
      float P21 = s14 - mX2*mW1*iz;
      float P22 = s15 - mX2*mW2*iz;
      float a00 = P00*P00 + P10*P10 + P20*P20;
      float a01 = P00*P01 + P10*P11 + P20*P21;
      float a02 = P00*P02 + P10*P12 + P20*P22;
      float a11 = P01*P01 + P11*P11 + P21*P21;
      float a12 = P01*P02 + P11*P12 + P21*P22;
      float a22 = P02*P02 + P12*P12 + P22*P22;
      float v00=1, v01=0, v02=0, v10=0, v11=1, v12=0, v20=0, v21=0, v22=1;
      #pragma unroll 1
      for (int sweep = 0; sweep < 8; sweep++) {
        JROTF(a00,a11,a01, a02,a12, v00,v10,v20, v01,v11,v21);
        JROTF(a00,a22,a02, a01,a12, v00,v10,v20, v02,v12,v22);
        JROTF(a11,a22,a12, a01,a02, v01,v11,v21, v02,v12,v22);
      }
      float l0 = a00, l1 = a11, l2 = a22;
      CSWAP3F(l0,l1, v00,v10,v20, v01,v11,v21);
      CSWAP3F(l1,l2, v01,v11,v21, v02,v12,v22);
      CSWAP3F(l0,l1, v00,v10,v20, v01,v11,v21);
      float detP = P00*(P11*P22-P12*P21) - P01*(P10*P22-P12*P20)
                 + P02*(P10*P21-P11*P20);
      float s2d = (detP < 0.0f) ? -1.0f : 1.0f;
      float tiny = 1e-18f*l0 + 1e-30f;
      float w0i = __builtin_amdgcn_rsqf(fmaxf(l0,tiny));
      float w1i = __builtin_amdgcn_rsqf(fmaxf(l1,tiny));
      float w2i = s2d*__builtin_amdgcn_rsqf(fmaxf(l2,tiny));
      float M00 = w0i*v00*v00 + w1i*v01*v01 + w2i*v02*v02;
      float M01 = w0i*v00*v10 + w1i*v01*v11 + w2i*v02*v12;
      float M02 = w0i*v00*v20 + w1i*v01*v21 + w2i*v02*v22;
      float M11 = w0i*v10*v10 + w1i*v11*v11 + w2i*v12*v12;
      float M12 = w0i*v10*v20 + w1i*v11*v21 + w2i*v12*v22;
      float M22 = w0i*v20*v20 + w1i*v21*v21 + w2i*v22*v22;
      float R00n = P00*M00 + P01*M01 + P02*M02;
      float R01n = P00*M01 + P01*M11 + P02*M12;
      float R02n = P00*M02 + P01*M12 + P02*M22;
      float R10n = P10*M00 + P11*M01 + P12*M02;
      float R11n = P10*M01 + P11*M11 + P12*M12;
      float R12n = P10*M02 + P11*M12 + P12*M22;
      float R20n = P20*M00 + P21*M01 + P22*M02;
      float R21n = P20*M01 + P21*M11 + P22*M12;
      float R22n = P20*M02 + P21*M12 + P22*M22;
      float tm0 = (mX0 - (R00n*mW0 + R01n*mW1 + R02n*mW2))*iz;
      float tm1 = (mX1 - (R10n*mW0 + R11n*mW1 + R12n*mW2))*iz;
      float tm2 = (mX2 - (R20n*mW0 + R21n*mW1 + R22n*mW2))*iz;
      sR[mm][0]=R00n; sR[mm][1]=R01n; sR[mm][2]=R02n;
      sR[mm][3]=R10n; sR[mm][4]=R11n; sR[mm][5]=R12n;
      sR[mm][6]=R20n; sR[mm][7]=R21n; sR[mm][8]=R22n;
      sT[mm][0]=tm0; sT[mm][1]=tm1; sT[mm][2]=tm2;
      sTn[mm] = tm0*tm0 + tm1*tm1 + tm2*tm2;
    }
    __syncthreads();
    if (tid < Kv) {
      float den = 0.f, Xn0=0.f, Xn1=0.f, Xn2=0.f, S2=0.f;
      #pragma unroll
      for (int mm=0;mm<Mv;mm++) {
        float r0 = sR[mm][0]*w0v[mm] + sR[mm][1]*w1v[mm] + sR[mm][2]*w2v[mm];
        float r1 = sR[mm][3]*w0v[mm] + sR[mm][4]*w1v[mm] + sR[mm][5]*w2v[mm];
        float r2 = sR[mm][6]*w0v[mm] + sR[mm][7]*w1v[mm] + sR[mm][8]*w2v[mm];
        float tt0 = sT[mm][0], tt1 = sT[mm][1], tt2 = sT[mm][2];
        den += lk[mm];
        Xn0 += r0 + tt0*lk[mm]; Xn1 += r1 + tt1*lk[mm]; Xn2 += r2 + tt2*lk[mm];
        S2  += hk[mm] + 2.f*(tt0*r0+tt1*r1+tt2*r2) + sTn[mm]*lk[mm];
      }
      float x0, x1, x2;
      if (it > 1) { float inv = __builtin_amdgcn_rcpf(den);
                    x0=Xn0*inv; x1=Xn1*inv; x2=Xn2*inv; }
      else        { x0=sX[k][0]; x1=sX[k][1]; x2=sX[k][2]; }
      float wn = S2 + (x0*x0+x1*x1+x2*x2)*den - 2.f*(x0*Xn0+x1*Xn1+x2*Xn2);
      float qn = 3.f*den / (wn + 3.f*den*EPSILON_C);
      sX[k][0]=x0; sX[k][1]=x1; sX[k][2]=x2;
      sQ[k] = qn;
    }
  }
  __syncthreads();
  // block 0 publishes final R/t/X for p3 (dispatch boundary = visibility)
  if (bid == 0) {
    if (tid < 72) ws[WS_R + tid] = ((float*)sR)[tid];
    if (tid < 24) ws[WS_T + tid] = ((float*)sT)[tid];
    if (tid < Kv) {
      ws[WS_X + 3*k+0] = sX[k][0];
      ws[WS_X + 3*k+1] = sX[k][1];
      ws[WS_X + 3*k+2] = sX[k][2];
    }
  }
}

// ---------------------------------------------------------------- final out
#define OUT_TOTAL (Mv*3*Nv + 72 + 24 + Kv*3)
__global__ __launch_bounds__(256) void p3_final(const float* __restrict__ Vs,
                                                const float* __restrict__ ws,
                                                float* __restrict__ out) {
  for (int idx = blockIdx.x*256 + threadIdx.x; idx < OUT_TOTAL; idx += 512*256) {
    if (idx < Mv*3*Nv) {
      int m = idx / (3*Nv);
      int r = idx % (3*Nv);
      int d = r / Nv;
      int n = r % Nv;
      float vx = Vs[(size_t)(m*3+0)*Nv + n];
      float vy = Vs[(size_t)(m*3+1)*Nv + n];
      float vz = Vs[(size_t)(m*3+2)*Nv + n];
      out[idx] = fmaf(ws[WS_R+m*9+d*3+0],vx,
                 fmaf(ws[WS_R+m*9+d*3+1],vy,
                 fmaf(ws[WS_R+m*9+d*3+2],vz, ws[WS_T+m*3+d])));
    } else {
      int j = idx - Mv*3*Nv;
      float v;
      if (j < 72)      v = ws[WS_R + j];
      else if (j < 96) v = ws[WS_T + (j-72)];
      else             v = ws[WS_X + (j-96)];
      out[idx] = v;
    }
  }
}

extern "C" void kernel_launch(void* const* d_in, const int* in_sizes, int n_in,
                              void* d_out, int out_size, void* d_ws, size_t ws_size,
                              hipStream_t stream) {
  const float* Vs = (const float*)d_in[0];
  const float* X0 = (const float*)d_in[1];
  const float* Q0 = (const float*)d_in[2];
  float* out = (float*)d_out;
  float* ws  = (float*)d_ws;

  p0_init<<<25, 256, 0, stream>>>(Vs, X0, Q0, ws);
  {
    void* args[] = { (void*)&Vs, (void*)&ws };
    hipLaunchCooperativeKernel((const void*)p_main, dim3(NBLK), dim3(TPB),
                               args, 0, stream);
  }
  p3_final<<<512, 256, 0, stream>>>(Vs, ws, out);
}

// Round 14
// 286.878 us; speedup vs baseline: 1.1611x; 1.1611x over previous
//
#include <hip/hip_runtime.h>
#include <math.h>

#define Mv 8
#define Nv 8192
#define Kv 256
#define BPM 64            // blocks per m -> 512 blocks per pA
#define NBLK (Mv*BPM)
#define NITER 6
#define EPSILON_C 0.01f
#define GAMMA_C 0.005f

// ws layout (float offsets). NO atomics anywhere; handoff data written with
// NON-TEMPORAL stores (never dirty in any XCD's L2 -> no cross-XCD
// probe-on-read, which cost ~25-35us/iter in R2-R13 via every mechanism).
#define WS_R     0        // 72   initial R (identity, p0)
#define WS_T     72       // 24   initial t (p0)
#define WS_XC    96       // 2x768  X state, parity-buffered
#define WS_QC    1632     // 2x256  Q state, parity-buffered
#define WS_BETA  2144     // 1
#define WS_TOT   2148     // 10240  totals [m][5][256] (nt, pB1)
#define WS_STATS 12388    // 128    [m][16]            (nt, pB1)
#define WS_PART  12516    // 655360 partials [m][blk][5][256] (nt, pA)

#define NTLD(p)   __builtin_nontemporal_load((p))
#define NTST(p,v) __builtin_nontemporal_store((v), (p))

// ---- wave-wide sum via DPP; wave-uniform result. All lanes active.
__device__ __forceinline__ float wave_red_sum(float x) {
  int v;
  float t;
  v = __builtin_bit_cast(int, x);
  t = __builtin_bit_cast(float, __builtin_amdgcn_update_dpp(0, v, 0x111, 0xf, 0xf, true));  // row_shr:1
  x += t; v = __builtin_bit_cast(int, x);
  t = __builtin_bit_cast(float, __builtin_amdgcn_update_dpp(0, v, 0x112, 0xf, 0xf, true));  // row_shr:2
  x += t; v = __builtin_bit_cast(int, x);
  t = __builtin_bit_cast(float, __builtin_amdgcn_update_dpp(0, v, 0x114, 0xf, 0xf, true));  // row_shr:4
  x += t; v = __builtin_bit_cast(int, x);
  t = __builtin_bit_cast(float, __builtin_amdgcn_update_dpp(0, v, 0x118, 0xf, 0xf, true));  // row_shr:8
  x += t; v = __builtin_bit_cast(int, x);
  t = __builtin_bit_cast(float, __builtin_amdgcn_update_dpp(0, v, 0x142, 0xa, 0xf, false)); // row_bcast:15
  x += t; v = __builtin_bit_cast(int, x);
  t = __builtin_bit_cast(float, __builtin_amdgcn_update_dpp(0, v, 0x143, 0xc, 0xf, false)); // row_bcast:31
  x += t;
  return __builtin_bit_cast(float, __builtin_amdgcn_readlane(__builtin_bit_cast(int, x), 63));
}

// ---------------------------------------------------------------- init
__global__ __launch_bounds__(256) void p0_init(const float* __restrict__ Vs,
                                               const float* __restrict__ X0,
                                               const float* __restrict__ Q0,
                                               float* __restrict__ ws) {
  __shared__ float sred[4];
  int tid = threadIdx.x;
  int b = blockIdx.x;
  int wave = tid >> 6, lane = tid & 63;
  if (b < 24) {
    int m = b / 3, d = b % 3;
    const float* src = Vs + (size_t)(m*3 + d) * Nv;
    float s = 0.f;
    for (int n = tid; n < Nv; n += 256) s += src[n];
    s = wave_red_sum(s);
    if (lane == 0) sred[wave] = s;
    __syncthreads();
    if (tid == 0) {
      float tot = sred[0]+sred[1]+sred[2]+sred[3];
      ws[WS_T + m*3 + d] = -tot / (float)Nv;
    }
    if (d == 0 && tid < 9) {
      ws[WS_R + m*9 + tid] = (tid==0||tid==4||tid==8) ? 1.f : 0.f;
    }
  } else {
    float s = (tid < Kv) ? Q0[tid] : 0.f;
    s = wave_red_sum(s);
    if (lane == 0) sred[wave] = s;
    __syncthreads();
    if (tid == 0) {
      float mq = (sred[0]+sred[1]+sred[2]+sred[3]) / (float)Kv;
      ws[WS_BETA] = GAMMA_C * mq * sqrtf(mq);
    }
    if (tid < Kv) ws[WS_QC + tid] = Q0[tid];           // QC parity 0
    for (int i = tid; i < Kv*3; i += 256) ws[WS_XC + i] = X0[i];  // XC parity 0
  }
}

// ---- fp32 Jacobi rotation, COMPILE-TIME pair, named scalars only.
#define JROTF(app,aqq,apq,apr,aqr, vp0,vp1,vp2, vq0,vq1,vq2) do {           \
    float tau_ = (aqq - app) * __builtin_amdgcn_rcpf(2.0f*apq);             \
    float tt_ = __builtin_amdgcn_rcpf(fabsf(tau_) +                         \
                   __builtin_amdgcn_sqrtf(fmaf(tau_,tau_,1.0f)));           \
    tt_ = (tau_ < 0.0f) ? -tt_ : tt_;                                       \
    tt_ = (apq == 0.0f) ? 0.0f : tt_;                                       \
    float c_ = __builtin_amdgcn_rsqf(fmaf(tt_,tt_,1.0f)), s_ = tt_*c_;      \
    float papq_ = apq;                                                      \
    app = fmaf(-tt_,papq_,app); aqq = fmaf(tt_,papq_,aqq); apq = 0.0f;      \
    float tp_ = apr, tq_ = aqr;                                             \
    apr = c_*tp_ - s_*tq_; aqr = s_*tp_ + c_*tq_;                           \
    tp_=vp0; tq_=vq0; vp0=c_*tp_-s_*tq_; vq0=s_*tp_+c_*tq_;                 \
    tp_=vp1; tq_=vq1; vp1=c_*tp_-s_*tq_; vq1=s_*tp_+c_*tq_;                 \
    tp_=vp2; tq_=vq2; vp2=c_*tp_-s_*tq_; vq2=s_*tp_+c_*tq_;                 \
  } while(0)

#define CSWAP3F(la,lb, a0,a1,a2, b0,b1,b2) do {                             \
    if (la < lb) { float t_;                                                \
      t_=la; la=lb; lb=t_; t_=a0; a0=b0; b0=t_;                             \
      t_=a1; a1=b1; b1=t_; t_=a2; a2=b2; b2=t_; }                           \
  } while(0)

// ---- redundant small update for iteration ITPREV from nt totals/stats.
// One internal __syncthreads; caller must sync after before reading others'
// sX/sQ.
template<int ITPREV>
__device__ __forceinline__ void small_update2(const float* __restrict__ ws,
                                              int tid,
                                              float (*sX)[3], float* sQ,
                                              float (*sR)[9], float (*sT)[3],
                                              float* sTn) {
  const int k = tid;
  float lk[Mv], w0v[Mv], w1v[Mv], w2v[Mv], hk[Mv];
  #pragma unroll
  for (int mm=0;mm<Mv;mm++) {
    const float* t5 = ws + WS_TOT + (mm*5)*Kv + k;
    lk[mm]  = NTLD(&t5[0*Kv]);
    w0v[mm] = NTLD(&t5[1*Kv]);
    w1v[mm] = NTLD(&t5[2*Kv]);
    w2v[mm] = NTLD(&t5[3*Kv]);
    hk[mm]  = NTLD(&t5[4*Kv]);
  }
  const float* xcp = ws + WS_XC + (ITPREV&1)*768;
  float xp0 = xcp[k*3+0], xp1 = xcp[k*3+1], xp2 = xcp[k*3+2];

  if (tid < Mv) {
    int mm = tid;
    const float* st = ws + WS_STATS + mm*16;
    float s0=NTLD(&st[0]), s1=NTLD(&st[1]), s2v=NTLD(&st[2]), s3=NTLD(&st[3]),
          s4=NTLD(&st[4]), s5=NTLD(&st[5]), s6=NTLD(&st[6]), s7=NTLD(&st[7]),
          s8=NTLD(&st[8]), s9=NTLD(&st[9]), s10=NTLD(&st[10]), s11=NTLD(&st[11]),
          s12=NTLD(&st[12]), s13=NTLD(&st[13]), s14=NTLD(&st[14]), s15=NTLD(&st[15]);
    float z = s0;
    float mX0 = s1, mX1 = s2v, mX2 = s3;
    float mW0 = s4, mW1 = s5, mW2 = s6;
    float iz = __builtin_amdgcn_rcpf(z);
    float P00 = s7  - mX0*mW0*iz;
    float P01 = s8  - mX0*mW1*iz;
    float P02 = s9  - mX0*mW2*iz;
    float P10 = s10 - mX1*mW0*iz;
    float P11 = s11 - mX1*mW1*iz;
    float P12 = s12 - mX1*mW2*iz;
    float P20 = s13 - mX2*mW0*iz;
    float P21 = s14 - mX2*mW1*iz;
    float P22 = s15 - mX2*mW2*iz;
    float a00 = P00*P00 + P10*P10 + P20*P20;
    float a01 = P00*P01 + P10*P11 + P20*P21;
    float a02 = P00*P02 + P10*P12 + P20*P22;
    float a11 = P01*P01 + P11*P11 + P21*P21;
    float a12 = P01*P02 + P11*P12 + P21*P22;
    float a22 = P02*P02 + P12*P12 + P22*P22;
    float v00=1, v01=0, v02=0, v10=0, v11=1, v12=0, v20=0, v21=0, v22=1;
    #pragma unroll 1
    for (int sweep = 0; sweep < 8; sweep++) {
      JROTF(a00,a11,a01, a02,a12, v00,v10,v20, v01,v11,v21);
      JROTF(a00,a22,a02, a01,a12, v00,v10,v20, v02,v12,v22);
      JROTF(a11,a22,a12, a01,a02, v01,v11,v21, v02,v12,v22);
    }
    float l0 = a00, l1 = a11, l2 = a22;
    CSWAP3F(l0,l1, v00,v10,v20, v01,v11,v21);
    CSWAP3F(l1,l2, v01,v11,v21, v02,v12,v22);
    CSWAP3F(l0,l1, v00,v10,v20, v01,v11,v21);
    float detP = P00*(P11*P22-P12*P21) - P01*(P10*P22-P12*P20)
               + P02*(P10*P21-P11*P20);
    float s2d = (detP < 0.0f) ? -1.0f : 1.0f;
    float tiny = 1e-18f*l0 + 1e-30f;
    float w0i = __builtin_amdgcn_rsqf(fmaxf(l0,tiny));
    float w1i = __builtin_amdgcn_rsqf(fmaxf(l1,tiny));
    float w2i = s2d*__builtin_amdgcn_rsqf(fmaxf(l2,tiny));
    float M00 = w0i*v00*v00 + w1i*v01*v01 + w2i*v02*v02;
    float M01 = w0i*v00*v10 + w1i*v01*v11 + w2i*v02*v12;
    float M02 = w0i*v00*v20 + w1i*v01*v21 + w2i*v02*v22;
    float M11 = w0i*v10*v10 + w1i*v11*v11 + w2i*v12*v12;
    float M12 = w0i*v10*v20 + w1i*v11*v21 + w2i*v12*v22;
    float M22 = w0i*v20*v20 + w1i*v21*v21 + w2i*v22*v22;
    float R00n = P00*M00 + P01*M01 + P02*M02;
    float R01n = P00*M01 + P01*M11 + P02*M12;
    float R02n = P00*M02 + P01*M12 + P02*M22;
    float R10n = P10*M00 + P11*M01 + P12*M02;
    float R11n = P10*M01 + P11*M11 + P12*M12;
    float R12n = P10*M02 + P11*M12 + P12*M22;
    float R20n = P20*M00 + P21*M01 + P22*M02;
    float R21n = P20*M01 + P21*M11 + P22*M12;
    float R22n = P20*M02 + P21*M12 + P22*M22;
    float tm0 = (mX0 - (R00n*mW0 + R01n*mW1 + R02n*mW2))*iz;
    float tm1 = (mX1 - (R10n*mW0 + R11n*mW1 + R12n*mW2))*iz;
    float tm2 = (mX2 - (R20n*mW0 + R21n*mW1 + R22n*mW2))*iz;
    sR[mm][0]=R00n; sR[mm][1]=R01n; sR[mm][2]=R02n;
    sR[mm][3]=R10n; sR[mm][4]=R11n; sR[mm][5]=R12n;
    sR[mm][6]=R20n; sR[mm][7]=R21n; sR[mm][8]=R22n;
    sT[mm][0]=tm0; sT[mm][1]=tm1; sT[mm][2]=tm2;
    sTn[mm] = tm0*tm0 + tm1*tm1 + tm2*tm2;
  }
  __syncthreads();
  {
    float den = 0.f, Xn0=0.f, Xn1=0.f, Xn2=0.f, S2=0.f;
    #pragma unroll
    for (int mm=0;mm<Mv;mm++) {
      float r0 = sR[mm][0]*w0v[mm] + sR[mm][1]*w1v[mm] + sR[mm][2]*w2v[mm];
      float r1 = sR[mm][3]*w0v[mm] + sR[mm][4]*w1v[mm] + sR[mm][5]*w2v[mm];
      float r2 = sR[mm][6]*w0v[mm] + sR[mm][7]*w1v[mm] + sR[mm][8]*w2v[mm];
      float tt0 = sT[mm][0], tt1 = sT[mm][1], tt2 = sT[mm][2];
      den += lk[mm];
      Xn0 += r0 + tt0*lk[mm]; Xn1 += r1 + tt1*lk[mm]; Xn2 += r2 + tt2*lk[mm];
      S2  += hk[mm] + 2.f*(tt0*r0+tt1*r1+tt2*r2) + sTn[mm]*lk[mm];
    }
    float x0, x1, x2;
    if (ITPREV > 1) { float inv = __builtin_amdgcn_rcpf(den);
                      x0=Xn0*inv; x1=Xn1*inv; x2=Xn2*inv; }
    else            { x0=xp0; x1=xp1; x2=xp2; }
    float wn = S2 + (x0*x0+x1*x1+x2*x2)*den - 2.f*(x0*Xn0+x1*Xn1+x2*Xn2);
    float qn = 3.f*den / (wn + 3.f*den*EPSILON_C);
    sX[k][0]=x0; sX[k][1]=x1; sX[k][2]=x2;
    sQ[k] = qn;
  }
}

// ------------------------------------------- phase-A kernel (512 blocks)
template<int IT>
__global__ __launch_bounds__(256) void pA(const float* __restrict__ Vs,
                                          float* __restrict__ ws) {
  __shared__ float sb[4][5][Kv]; // 20 KB
  __shared__ float sX[Kv][3];
  __shared__ float sQ[Kv];
  __shared__ float sR[Mv][9];
  __shared__ float sT[Mv][3];
  __shared__ float sTn[Mv];

  int tid  = threadIdx.x;
  int wave = tid >> 6, lane = tid & 63;
  int bid  = blockIdx.x;
  int m    = bid / BPM;
  int blk  = bid % BPM;
  int wid  = blk*4 + wave;
  const int k = tid;
  float beta = ws[WS_BETA];

  if (IT == 0) {
    if (tid < 72) ((float*)sR)[tid] = ws[WS_R + tid];
    if (tid < 24) ((float*)sT)[tid] = ws[WS_T + tid];
    sX[k][0] = ws[WS_XC + 3*k+0];
    sX[k][1] = ws[WS_XC + 3*k+1];
    sX[k][2] = ws[WS_XC + 3*k+2];
    sQ[k]    = ws[WS_QC + k];
  } else {
    small_update2<(IT > 0) ? (IT-1) : 0>(ws, tid, sX, sQ, sR, sT, sTn);
  }
  __syncthreads();
  if (IT > 0 && bid == 0) {   // persist X/Q for pB1(IT) and pA(IT+1)
    float* xcn = ws + WS_XC + (IT&1)*768;
    xcn[k*3+0]=sX[k][0]; xcn[k*3+1]=sX[k][1]; xcn[k*3+2]=sX[k][2];
    ws[WS_QC + (IT&1)*Kv + k] = sQ[k];
  }

  // ---- phase A
  float R00=sR[m][0],R01=sR[m][1],R02=sR[m][2];
  float R10=sR[m][3],R11=sR[m][4],R12=sR[m][5];
  float R20=sR[m][6],R21=sR[m][7],R22=sR[m][8];
  float t0=sT[m][0], t1=sT[m][1], t2=sT[m][2];
  float kXx[4],kXy[4],kXz[4],kA[4],kB[4],kQ[4],kQ32[4];
  #pragma unroll
  for (int j=0;j<4;j++) {
    int kk = lane + 64*j;
    float xx = sX[kk][0], xy = sX[kk][1], xz = sX[kk][2];
    float q  = sQ[kk];
    kXx[j]=xx; kXy[j]=xy; kXz[j]=xz;
    kA[j]  = -0.5f*q;
    kB[j]  = kA[j]*(xx*xx+xy*xy+xz*xz);
    kQ[j]  = q;
    kQ32[j]= q*sqrtf(q);
  }
  float aL[4]={0,0,0,0}, aWx[4]={0,0,0,0}, aWy[4]={0,0,0,0},
        aWz[4]={0,0,0,0}, aH[4]={0,0,0,0};
  const float* V0 = Vs + (size_t)(m*3+0)*Nv;
  const float* V1 = Vs + (size_t)(m*3+1)*Nv;
  const float* V2 = Vs + (size_t)(m*3+2)*Nv;
  for (int n = wid; n < Nv; n += 256) {
    float vx = V0[n], vy = V1[n], vz = V2[n];
    float px = fmaf(R00,vx, fmaf(R01,vy, fmaf(R02,vz, t0)));
    float py = fmaf(R10,vx, fmaf(R11,vy, fmaf(R12,vz, t1)));
    float pz = fmaf(R20,vx, fmaf(R21,vy, fmaf(R22,vz, t2)));
    float tvn = fmaf(px,px, fmaf(py,py, pz*pz));
    float vn  = fmaf(vx,vx, fmaf(vy,vy, vz*vz));
    float ap[4]; float s = 0.f;
    #pragma unroll
    for (int j=0;j<4;j++) {
      float dot = fmaf(px,kXx[j], fmaf(py,kXy[j], pz*kXz[j]));
      float arg = fmaf(kQ[j], dot, fmaf(kA[j], tvn, kB[j]));
      float e = __expf(arg)*kQ32[j];
      ap[j] = e; s += e;
    }
    float S = wave_red_sum(s);
    float inv = __builtin_amdgcn_rcpf(S + beta);
    #pragma unroll
    for (int j=0;j<4;j++) {
      float a = ap[j]*inv;
      aL[j] += a;
      aWx[j] = fmaf(a,vx,aWx[j]);
      aWy[j] = fmaf(a,vy,aWy[j]);
      aWz[j] = fmaf(a,vz,aWz[j]);
      aH[j]  = fmaf(a,vn,aH[j]);
    }
  }
  #pragma unroll
  for (int j=0;j<4;j++) {
    int kk = lane + 64*j;
    sb[wave][0][kk]=aL[j];  sb[wave][1][kk]=aWx[j]; sb[wave][2][kk]=aWy[j];
    sb[wave][3][kk]=aWz[j]; sb[wave][4][kk]=aH[j];
  }
  __syncthreads();
  // non-temporal coalesced partial stores: part[m][blk][q][k]
  float* pb = ws + WS_PART + (size_t)((m*BPM + blk)*5)*Kv;
  NTST(&pb[0*Kv + k], sb[0][0][k]+sb[1][0][k]+sb[2][0][k]+sb[3][0][k]);
  NTST(&pb[1*Kv + k], sb[0][1][k]+sb[1][1][k]+sb[2][1][k]+sb[3][1][k]);
  NTST(&pb[2*Kv + k], sb[0][2][k]+sb[1][2][k]+sb[2][2][k]+sb[3][2][k]);
  NTST(&pb[3*Kv + k], sb[0][3][k]+sb[1][3][k]+sb[2][3][k]+sb[3][3][k]);
  NTST(&pb[4*Kv + k], sb[0][4][k]+sb[1][4][k]+sb[2][4][k]+sb[3][4][k]);
}

// ---------------- reduce partials -> totals + 16 per-m stats (8 blocks)
__global__ __launch_bounds__(256) void pB1(float* __restrict__ ws, int par) {
  __shared__ float st4[4][16];
  int tid = threadIdx.x;
  int wave = tid >> 6, lane = tid & 63;
  int m = blockIdx.x;
  float tL=0.f, tWx=0.f, tWy=0.f, tWz=0.f, tH=0.f;
  const float* P = ws + WS_PART + (size_t)(m*BPM*5)*Kv;
  #pragma unroll 4
  for (int blk = 0; blk < BPM; ++blk) {
    const float* b = P + blk*5*Kv;
    tL  += NTLD(&b[0*Kv + tid]);
    tWx += NTLD(&b[1*Kv + tid]);
    tWy += NTLD(&b[2*Kv + tid]);
    tWz += NTLD(&b[3*Kv + tid]);
    tH  += NTLD(&b[4*Kv + tid]);
  }
  float* t5 = ws + WS_TOT + (m*5)*Kv + tid;
  NTST(&t5[0*Kv], tL); NTST(&t5[1*Kv], tWx); NTST(&t5[2*Kv], tWy);
  NTST(&t5[3*Kv], tWz); NTST(&t5[4*Kv], tH);

  // 16 per-m stats from totals (linear in L/W)
  float q  = ws[WS_QC + par*Kv + tid];
  const float* xc = ws + WS_XC + par*768;
  float x0 = xc[tid*3+0], x1 = xc[tid*3+1], x2 = xc[tid*3+2];
  float bk = tL*q;
  float sw0 = tWx*q, sw1 = tWy*q, sw2 = tWz*q;
  float pr[16];
  pr[0]=bk;  pr[1]=bk*x0; pr[2]=bk*x1; pr[3]=bk*x2;
  pr[4]=sw0; pr[5]=sw1;   pr[6]=sw2;
  pr[7]=sw0*x0;  pr[8]=sw1*x0;  pr[9]=sw2*x0;
  pr[10]=sw0*x1; pr[11]=sw1*x1; pr[12]=sw2*x1;
  pr[13]=sw0*x2; pr[14]=sw1*x2; pr[15]=sw2*x2;
  float red[16];
  #pragma unroll
  for (int v2=0; v2<16; v2++) red[v2] = wave_red_sum(pr[v2]);
  if (lane == 0) {
    #pragma unroll
    for (int v2=0; v2<16; v2++) st4[wave][v2] = red[v2];
  }
  __syncthreads();
  if (tid < 16)
    NTST(&ws[WS_STATS + m*16 + tid],
         st4[0][tid]+st4[1][tid]+st4[2][tid]+st4[3][tid]);
}

// ------------------------------- final: prologue finalizes iter 5, write out
#define OUT_TOTAL (Mv*3*Nv + 72 + 24 + Kv*3)
__global__ __launch_bounds__(256) void p3_final(const float* __restrict__ Vs,
                                                const float* __restrict__ ws,
                                                float* __restrict__ out) {
  __shared__ float sX[Kv][3];
  __shared__ float sQ[Kv];
  __shared__ float sR[Mv][9];
  __shared__ float sT[Mv][3];
  __shared__ float sTn[Mv];
  int tid = threadIdx.x;
  small_update2<NITER-1>(ws, tid, sX, sQ, sR, sT, sTn);
  __syncthreads();

  for (int idx = blockIdx.x*256 + tid; idx < OUT_TOTAL; idx += 512*256) {
    if (idx < Mv*3*Nv) {
      int m = idx / (3*Nv);
      int r = idx % (3*Nv);
      int d = r / Nv;
      int n = r % Nv;
      float vx = Vs[(size_t)(m*3+0)*Nv + n];
      float vy = Vs[(size_t)(m*3+1)*Nv + n];
      float vz = Vs[(size_t)(m*3+2)*Nv + n];
      out[idx] = fmaf(sR[m][d*3+0],vx,
                 fmaf(sR[m][d*3+1],vy,
                 fmaf(sR[m][d*3+2],vz, sT[m][d])));
    } else {
      int j = idx - Mv*3*Nv;
      float v;
      if (j < 72)      v = ((float*)sR)[j];
      else if (j < 96) v = ((float*)sT)[j-72];
      else             v = ((float*)sX)[j-96];
      out[idx] = v;
    }
  }
}

extern "C" void kernel_launch(void* const* d_in, const int* in_sizes, int n_in,
                              void* d_out, int out_size, void* d_ws, size_t ws_size,
                              hipStream_t stream) {
  const float* Vs = (const float*)d_in[0];
  const float* X0 = (const float*)d_in[1];
  const float* Q0 = (const float*)d_in[2];
  float* out = (float*)d_out;
  float* ws  = (float*)d_ws;

  p0_init<<<25, 256, 0, stream>>>(Vs, X0, Q0, ws);
  pA<0><<<NBLK, 256, 0, stream>>>(Vs, ws);
  pB1<<<Mv, 256, 0, stream>>>(ws, 0);
  pA<1><<<NBLK, 256, 0, stream>>>(Vs, ws);
  pB1<<<Mv, 256, 0, stream>>>(ws, 1);
  pA<2><<<NBLK, 256, 0, stream>>>(Vs, ws);
  pB1<<<Mv, 256, 0, stream>>>(ws, 0);
  pA<3><<<NBLK, 256, 0, stream>>>(Vs, ws);
  pB1<<<Mv, 256, 0, stream>>>(ws, 1);
  pA<4><<<NBLK, 256, 0, stream>>>(Vs, ws);
  pB1<<<Mv, 256, 0, stream>>>(ws, 0);
  pA<5><<<NBLK, 256, 0, stream>>>(Vs, ws);
  pB1<<<Mv, 256, 0, stream>>>(ws, 1);
  p3_final<<<512, 256, 0, stream>>>(Vs, ws, out);
}